// Round 2
// baseline (544.846 us; speedup 1.0000x reference)
//
#include <hip/hip_runtime.h>
#include <hip/hip_bf16.h>

#define NN 100000      // nodes
#define NE 3200000     // edges
#define NF 256         // in/out features

static __device__ __forceinline__ float bf2f(unsigned short u) {
    union { unsigned int i; float f; } c;
    c.i = ((unsigned int)u) << 16;
    return c.f;
}

// support[M][256] (bf16) = x[M][256] (f32) @ w[256][256] (f32)
// Block: 256 threads, 16 rows per block. Thread t owns output column t,
// 16 f32 accumulators. x reads are block-uniform -> scalar loads.
__global__ __launch_bounds__(256) void gemm_xw(const float* __restrict__ x,
                                               const float* __restrict__ w,
                                               __hip_bfloat16* __restrict__ support) {
    const int col  = threadIdx.x;
    const int row0 = blockIdx.x * 16;
    float acc[16];
#pragma unroll
    for (int r = 0; r < 16; ++r) acc[r] = 0.0f;

    const float* xp = x + (size_t)row0 * NF;
#pragma unroll 4
    for (int k = 0; k < NF; ++k) {
        const float wv = w[k * NF + col];   // coalesced, L2-resident
#pragma unroll
        for (int r = 0; r < 16; ++r)
            acc[r] = fmaf(xp[r * NF + k], wv, acc[r]);  // xp[...] uniform -> s_load
    }
#pragma unroll
    for (int r = 0; r < 16; ++r)
        support[(size_t)(row0 + r) * NF + col] = __float2bfloat16(acc[r]);
}

// CSR row pointers from sorted edge_row (int32 — harness passes integers as int32).
__global__ void build_rowptr(const int* __restrict__ erow,
                             int* __restrict__ rowptr) {
    int e = blockIdx.x * blockDim.x + threadIdx.x;
    if (e >= NE) return;
    int r    = erow[e];
    int prev = (e == 0) ? -1 : erow[e - 1];
    for (int q = prev + 1; q <= r; ++q) rowptr[q] = e;
    if (e == NE - 1) {
        for (int q = r + 1; q <= NN; ++q) rowptr[q] = NE;
    }
}

// out[row][:] = sum_e val[e] * support[col[e]][:]  + bias
// One wave per row; lane owns 4 consecutive features (8B bf16 gather/lane).
__global__ __launch_bounds__(256) void spmm(const __hip_bfloat16* __restrict__ support,
                                            const int* __restrict__ rowptr,
                                            const int* __restrict__ ecol,
                                            const float* __restrict__ eval,
                                            const float* __restrict__ bias,
                                            float* __restrict__ out) {
    const int wave = threadIdx.x >> 6;
    const int lane = threadIdx.x & 63;
    const int row  = blockIdx.x * 4 + wave;
    const int f    = lane * 4;

    const int s = rowptr[row];
    const int e = rowptr[row + 1];

    float a0 = 0.f, a1 = 0.f, a2 = 0.f, a3 = 0.f;
    const unsigned short* sp = reinterpret_cast<const unsigned short*>(support);

#pragma unroll 4
    for (int i = s; i < e; ++i) {
        const int   c = ecol[i];        // wave-uniform -> scalar load
        const float v = eval[i];        // wave-uniform -> scalar load
        const ushort4 sv = *reinterpret_cast<const ushort4*>(sp + (size_t)c * NF + f);
        a0 = fmaf(v, bf2f(sv.x), a0);
        a1 = fmaf(v, bf2f(sv.y), a1);
        a2 = fmaf(v, bf2f(sv.z), a2);
        a3 = fmaf(v, bf2f(sv.w), a3);
    }

    const float4 b = *reinterpret_cast<const float4*>(bias + f);
    float4 o;
    o.x = a0 + b.x; o.y = a1 + b.y; o.z = a2 + b.z; o.w = a3 + b.w;
    *reinterpret_cast<float4*>(out + (size_t)row * NF + f) = o;
}

extern "C" void kernel_launch(void* const* d_in, const int* in_sizes, int n_in,
                              void* d_out, int out_size, void* d_ws, size_t ws_size,
                              hipStream_t stream) {
    const float* x    = (const float*)d_in[0];
    const int*   erow = (const int*)d_in[1];
    const int*   ecol = (const int*)d_in[2];
    const float* eval = (const float*)d_in[3];
    const float* w    = (const float*)d_in[4];
    const float* bias = (const float*)d_in[5];
    float*       out  = (float*)d_out;

    __hip_bfloat16* support = (__hip_bfloat16*)d_ws;                       // 51.2 MB
    int* rowptr = (int*)((char*)d_ws + (size_t)NN * NF * sizeof(__hip_bfloat16));

    gemm_xw<<<NN / 16, 256, 0, stream>>>(x, w, support);
    build_rowptr<<<(NE + 255) / 256, 256, 0, stream>>>(erow, rowptr);
    spmm<<<NN / 4, 256, 0, stream>>>(support, rowptr, ecol, eval, bias, out);
}

// Round 3
// 316.215 us; speedup vs baseline: 1.7230x; 1.7230x over previous
//
#include <hip/hip_runtime.h>
#include <hip/hip_bf16.h>

#define NN 100000      // nodes
#define NE 3200000     // edges
#define NF 256         // features

typedef __attribute__((ext_vector_type(8))) __bf16 bf16x8;
typedef __attribute__((ext_vector_type(4))) float  f32x4;

static __device__ __forceinline__ float bf2f(unsigned short u) {
    union { unsigned int i; float f; } c;
    c.i = ((unsigned int)u) << 16;
    return c.f;
}

// Reorder W[256][256] (f32) into per-lane MFMA B-fragments (bf16):
// wfrag[(ks*16 + nf)*64 + lane][8] = W[k = ks*32 + (lane>>4)*8 + j][col = nf*16 + (lane&15)]
// Same k-map as the A-fragment build below -> consistent permutation cancels.
__global__ __launch_bounds__(256) void prep_w(const float* __restrict__ w,
                                              __bf16* __restrict__ wfrag) {
    const int t = blockIdx.x * 256 + threadIdx.x;   // 8192 total
    const int lane = t & 63;
    const int nf   = (t >> 6) & 15;
    const int ks   = t >> 10;
    const int col  = nf * 16 + (lane & 15);
    const int k0   = ks * 32 + (lane >> 4) * 8;
    bf16x8 v;
#pragma unroll
    for (int j = 0; j < 8; ++j) v[j] = (__bf16)w[(k0 + j) * NF + col];
    reinterpret_cast<bf16x8*>(wfrag)[t] = v;
}

// support[100000][256] (bf16) = x (f32) @ W via mfma_f32_16x16x32_bf16.
// Block: 5 waves x 16 rows = 80 rows; each wave does 16 rows x 256 cols
// (16 accumulators). 1250 blocks, no tail.
__global__ __launch_bounds__(320) void gemm_mfma(const float* __restrict__ x,
                                                 const __bf16* __restrict__ wfrag,
                                                 __bf16* __restrict__ support) {
    const int wv   = threadIdx.x >> 6;
    const int lane = threadIdx.x & 63;
    const int row0 = blockIdx.x * 80 + wv * 16;

    f32x4 acc[16];
#pragma unroll
    for (int nf = 0; nf < 16; ++nf) acc[nf] = (f32x4){0.f, 0.f, 0.f, 0.f};

    // A-fragment source: row = row0 + (lane&15), k0 = ks*32 + (lane>>4)*8
    const float* xp = x + (size_t)(row0 + (lane & 15)) * NF + ((lane >> 4) << 3);
    const bf16x8* wf = reinterpret_cast<const bf16x8*>(wfrag);

#pragma unroll
    for (int ks = 0; ks < 8; ++ks) {
        const float4 a0 = *reinterpret_cast<const float4*>(xp + ks * 32);
        const float4 a1 = *reinterpret_cast<const float4*>(xp + ks * 32 + 4);
        bf16x8 af;
        af[0] = (__bf16)a0.x; af[1] = (__bf16)a0.y;
        af[2] = (__bf16)a0.z; af[3] = (__bf16)a0.w;
        af[4] = (__bf16)a1.x; af[5] = (__bf16)a1.y;
        af[6] = (__bf16)a1.z; af[7] = (__bf16)a1.w;
#pragma unroll
        for (int nf = 0; nf < 16; ++nf) {
            const bf16x8 bfr = wf[(ks * 16 + nf) * 64 + lane];
            acc[nf] = __builtin_amdgcn_mfma_f32_16x16x32_bf16(af, bfr, acc[nf], 0, 0, 0);
        }
    }

    // C/D layout (m89-verified): col = lane&15, row = (lane>>4)*4 + reg
    const int crow = row0 + ((lane >> 4) << 2);
    const int ccol = lane & 15;
#pragma unroll
    for (int nf = 0; nf < 16; ++nf) {
#pragma unroll
        for (int r = 0; r < 4; ++r)
            support[(size_t)(crow + r) * NF + nf * 16 + ccol] = (__bf16)acc[nf][r];
    }
}

// CSR row pointers from sorted edge_row (int32).
__global__ void build_rowptr(const int* __restrict__ erow,
                             int* __restrict__ rowptr) {
    int e = blockIdx.x * blockDim.x + threadIdx.x;
    if (e >= NE) return;
    int r    = erow[e];
    int prev = (e == 0) ? -1 : erow[e - 1];
    for (int q = prev + 1; q <= r; ++q) rowptr[q] = e;
    if (e == NE - 1) {
        for (int q = r + 1; q <= NN; ++q) rowptr[q] = NE;
    }
}

// out[row][:] = sum_e val[e] * support[col[e]][:] + bias ; one wave per row.
__global__ __launch_bounds__(256) void spmm(const __bf16* __restrict__ support,
                                            const int* __restrict__ rowptr,
                                            const int* __restrict__ ecol,
                                            const float* __restrict__ eval,
                                            const float* __restrict__ bias,
                                            float* __restrict__ out) {
    const int wave = threadIdx.x >> 6;
    const int lane = threadIdx.x & 63;
    const int row  = blockIdx.x * 4 + wave;
    const int f    = lane * 4;

    const int s = rowptr[row];
    const int e = rowptr[row + 1];

    float a0 = 0.f, a1 = 0.f, a2 = 0.f, a3 = 0.f;
    const unsigned short* sp = reinterpret_cast<const unsigned short*>(support);

#pragma unroll 4
    for (int i = s; i < e; ++i) {
        const int   c = ecol[i];        // wave-uniform -> scalar load
        const float v = eval[i];        // wave-uniform -> scalar load
        const ushort4 sv = *reinterpret_cast<const ushort4*>(sp + (size_t)c * NF + f);
        a0 = fmaf(v, bf2f(sv.x), a0);
        a1 = fmaf(v, bf2f(sv.y), a1);
        a2 = fmaf(v, bf2f(sv.z), a2);
        a3 = fmaf(v, bf2f(sv.w), a3);
    }

    const float4 b = *reinterpret_cast<const float4*>(bias + f);
    float4 o;
    o.x = a0 + b.x; o.y = a1 + b.y; o.z = a2 + b.z; o.w = a3 + b.w;
    *reinterpret_cast<float4*>(out + (size_t)row * NF + f) = o;
}

extern "C" void kernel_launch(void* const* d_in, const int* in_sizes, int n_in,
                              void* d_out, int out_size, void* d_ws, size_t ws_size,
                              hipStream_t stream) {
    const float* x    = (const float*)d_in[0];
    const int*   erow = (const int*)d_in[1];
    const int*   ecol = (const int*)d_in[2];
    const float* eval = (const float*)d_in[3];
    const float* w    = (const float*)d_in[4];
    const float* bias = (const float*)d_in[5];
    float*       out  = (float*)d_out;

    __bf16* support = (__bf16*)d_ws;                                   // 51,200,000 B
    int*    rowptr  = (int*)((char*)d_ws + 51200000);                  // 400,004 B
    __bf16* wfrag   = (__bf16*)((char*)d_ws + 51600016);               // 131,072 B

    prep_w<<<32, 256, 0, stream>>>(w, wfrag);
    build_rowptr<<<(NE + 255) / 256, 256, 0, stream>>>(erow, rowptr);
    gemm_mfma<<<NN / 80, 320, 0, stream>>>(x, wfrag, support);
    spmm<<<NN / 4, 256, 0, stream>>>(support, rowptr, ecol, eval, bias, out);
}